// Round 4
// baseline (45.596 us; speedup 1.0000x reference)
//
#include <hip/hip_runtime.h>
#include <math.h>

// Nadaraya-Watson kernel regression, N=8192 rows, K=4096, f32.
//   out[n] = sum_k softmax(-0.5*((q[n]-keys[n,k])*w)^2)[k] * values[n,k]
//
// R3/R4 theory: keys+values = exactly 256 MiB = Infinity Cache capacity.
// Replayed streaming at 100.03% of LLC capacity thrashes LRU (FETCH_SIZE
// ~134 MB/replay). Mark the value-rows [6656,8192) (24 MiB) non-temporal so
// the remaining 232 MiB becomes LLC-resident across graph replays; steady
// state then reads 232 MiB from L3 + 24 MiB from HBM.

#define N_ROWS   8192
#define K_DIM    4096
#define BLOCK    256
#define CHUNKS   (K_DIM / (BLOCK * 4))   // 4 float4 chunks per thread
#define NT_START 6656                    // rows whose VALUES stream (non-temporal)

typedef float fvec4 __attribute__((ext_vector_type(4)));

template <bool NT>
__global__ __launch_bounds__(BLOCK) void nw_regression_kernel(
    const float* __restrict__ queries,
    const float* __restrict__ keys,
    const float* __restrict__ values,
    const float* __restrict__ w,
    float* __restrict__ out,
    int rowOffset)
{
    const int row  = blockIdx.x + rowOffset;
    const int tid  = threadIdx.x;
    const int wave = tid >> 6;
    const int lane = tid & 63;

    const float qv = queries[row];
    const float wv = w[0];

    const fvec4* krow = reinterpret_cast<const fvec4*>(keys   + (size_t)row * K_DIM);
    const fvec4* vrow = reinterpret_cast<const fvec4*>(values + (size_t)row * K_DIM);

    // Phase 1: keys -> scores in registers, track local max (scores <= 0).
    float sc[CHUNKS][4];
    float lmax = -3.402823466e38f;
    #pragma unroll
    for (int j = 0; j < CHUNKS; ++j) {
        fvec4 k4 = krow[tid + j * BLOCK];
        float d0 = (qv - k4.x) * wv;
        float d1 = (qv - k4.y) * wv;
        float d2 = (qv - k4.z) * wv;
        float d3 = (qv - k4.w) * wv;
        sc[j][0] = -0.5f * d0 * d0;
        sc[j][1] = -0.5f * d1 * d1;
        sc[j][2] = -0.5f * d2 * d2;
        sc[j][3] = -0.5f * d3 * d3;
        lmax = fmaxf(lmax, fmaxf(fmaxf(sc[j][0], sc[j][1]), fmaxf(sc[j][2], sc[j][3])));
    }

    #pragma unroll
    for (int off = 32; off > 0; off >>= 1)
        lmax = fmaxf(lmax, __shfl_down(lmax, off));

    __shared__ float smax[4];
    __shared__ float ssum[4];
    __shared__ float sdot[4];
    if (lane == 0) smax[wave] = lmax;
    __syncthreads();
    const float m = fmaxf(fmaxf(smax[0], smax[1]), fmaxf(smax[2], smax[3]));

    // Phase 2: values (non-temporal for the NT slice) fused with exp + dot.
    const float LOG2E = 1.442695040888963f;
    float lsum = 0.0f, ldot = 0.0f;
    #pragma unroll
    for (int j = 0; j < CHUNKS; ++j) {
        fvec4 v4;
        if (NT) v4 = __builtin_nontemporal_load(&vrow[tid + j * BLOCK]);
        else    v4 = vrow[tid + j * BLOCK];
        float p0 = __builtin_amdgcn_exp2f((sc[j][0] - m) * LOG2E);
        float p1 = __builtin_amdgcn_exp2f((sc[j][1] - m) * LOG2E);
        float p2 = __builtin_amdgcn_exp2f((sc[j][2] - m) * LOG2E);
        float p3 = __builtin_amdgcn_exp2f((sc[j][3] - m) * LOG2E);
        lsum += (p0 + p1) + (p2 + p3);
        ldot = fmaf(p0, v4.x, ldot);
        ldot = fmaf(p1, v4.y, ldot);
        ldot = fmaf(p2, v4.z, ldot);
        ldot = fmaf(p3, v4.w, ldot);
    }

    #pragma unroll
    for (int off = 32; off > 0; off >>= 1) {
        lsum += __shfl_down(lsum, off);
        ldot += __shfl_down(ldot, off);
    }
    if (lane == 0) { ssum[wave] = lsum; sdot[wave] = ldot; }
    __syncthreads();

    if (tid == 0) {
        float S = (ssum[0] + ssum[1]) + (ssum[2] + ssum[3]);
        float D = (sdot[0] + sdot[1]) + (sdot[2] + sdot[3]);
        out[row] = D / S;
    }
}

extern "C" void kernel_launch(void* const* d_in, const int* in_sizes, int n_in,
                              void* d_out, int out_size, void* d_ws, size_t ws_size,
                              hipStream_t stream) {
    const float* queries = (const float*)d_in[0];
    const float* keys    = (const float*)d_in[1];
    const float* values  = (const float*)d_in[2];
    const float* w       = (const float*)d_in[3];
    float* out = (float*)d_out;

    // Rows [0, NT_START): normal (LLC-resident). Rows [NT_START, N): values
    // load non-temporal so they don't evict the resident set.
    nw_regression_kernel<false><<<NT_START, BLOCK, 0, stream>>>(
        queries, keys, values, w, out, 0);
    nw_regression_kernel<true><<<N_ROWS - NT_START, BLOCK, 0, stream>>>(
        queries, keys, values, w, out, NT_START);
}

// Round 6
// 43.347 us; speedup vs baseline: 1.0519x; 1.0519x over previous
//
#include <hip/hip_runtime.h>
#include <math.h>

// Nadaraya-Watson kernel regression, N=8192 rows, K=4096, f32.
//   out[n] = sum_k softmax(-0.5*((q[n]-keys[n,k])*w)^2)[k] * values[n,k]
//
// Final form (= R2, best passing variant, 43.8 us):
//  - one block (4 waves) per row; coalesced dwordx4 loads
//  - phase 1: keys -> scores in registers + block max (exact softmax)
//  - phase 2: exp2(score-m) fused with value loads, sum + dot
//  - 268.4 MB mandatory traffic / ~6.3 TB/s achievable => ~43 us roofline.
// R5 ablation showed removing the barrier/max-sub gains only ~1.4% (noise)
// and destabilizes the post-timing re-validation; keep the exact-softmax
// two-phase structure.

#define N_ROWS 8192
#define K_DIM  4096
#define BLOCK  256
#define CHUNKS (K_DIM / (BLOCK * 4))   // 4 float4 chunks per thread

__global__ __launch_bounds__(BLOCK) void nw_regression_kernel(
    const float* __restrict__ queries,
    const float* __restrict__ keys,
    const float* __restrict__ values,
    const float* __restrict__ w,
    float* __restrict__ out)
{
    const int row  = blockIdx.x;
    const int tid  = threadIdx.x;
    const int wave = tid >> 6;
    const int lane = tid & 63;

    const float qv = queries[row];
    const float wv = w[0];

    const float4* krow = reinterpret_cast<const float4*>(keys   + (size_t)row * K_DIM);
    const float4* vrow = reinterpret_cast<const float4*>(values + (size_t)row * K_DIM);

    // Phase 1: keys -> scores in registers, track local max (scores <= 0).
    float sc[CHUNKS][4];
    float lmax = -3.402823466e38f;
    #pragma unroll
    for (int j = 0; j < CHUNKS; ++j) {
        float4 k4 = krow[tid + j * BLOCK];
        float d0 = (qv - k4.x) * wv;
        float d1 = (qv - k4.y) * wv;
        float d2 = (qv - k4.z) * wv;
        float d3 = (qv - k4.w) * wv;
        sc[j][0] = -0.5f * d0 * d0;
        sc[j][1] = -0.5f * d1 * d1;
        sc[j][2] = -0.5f * d2 * d2;
        sc[j][3] = -0.5f * d3 * d3;
        lmax = fmaxf(lmax, fmaxf(fmaxf(sc[j][0], sc[j][1]), fmaxf(sc[j][2], sc[j][3])));
    }

    // Block max: shfl within wave, LDS across the 4 waves.
    #pragma unroll
    for (int off = 32; off > 0; off >>= 1)
        lmax = fmaxf(lmax, __shfl_down(lmax, off));

    __shared__ float smax[4];
    __shared__ float ssum[4];
    __shared__ float sdot[4];
    if (lane == 0) smax[wave] = lmax;
    __syncthreads();
    const float m = fmaxf(fmaxf(smax[0], smax[1]), fmaxf(smax[2], smax[3]));

    // Phase 2: exp(score - m) fused with value loads; accumulate sum + dot.
    const float LOG2E = 1.442695040888963f;
    float lsum = 0.0f, ldot = 0.0f;
    #pragma unroll
    for (int j = 0; j < CHUNKS; ++j) {
        float4 v4 = vrow[tid + j * BLOCK];
        float p0 = __builtin_amdgcn_exp2f((sc[j][0] - m) * LOG2E);
        float p1 = __builtin_amdgcn_exp2f((sc[j][1] - m) * LOG2E);
        float p2 = __builtin_amdgcn_exp2f((sc[j][2] - m) * LOG2E);
        float p3 = __builtin_amdgcn_exp2f((sc[j][3] - m) * LOG2E);
        lsum += (p0 + p1) + (p2 + p3);
        ldot = fmaf(p0, v4.x, ldot);
        ldot = fmaf(p1, v4.y, ldot);
        ldot = fmaf(p2, v4.z, ldot);
        ldot = fmaf(p3, v4.w, ldot);
    }

    #pragma unroll
    for (int off = 32; off > 0; off >>= 1) {
        lsum += __shfl_down(lsum, off);
        ldot += __shfl_down(ldot, off);
    }
    if (lane == 0) { ssum[wave] = lsum; sdot[wave] = ldot; }
    __syncthreads();

    if (tid == 0) {
        float S = (ssum[0] + ssum[1]) + (ssum[2] + ssum[3]);
        float D = (sdot[0] + sdot[1]) + (sdot[2] + sdot[3]);
        out[row] = D / S;
    }
}

extern "C" void kernel_launch(void* const* d_in, const int* in_sizes, int n_in,
                              void* d_out, int out_size, void* d_ws, size_t ws_size,
                              hipStream_t stream) {
    const float* queries = (const float*)d_in[0];
    const float* keys    = (const float*)d_in[1];
    const float* values  = (const float*)d_in[2];
    const float* w       = (const float*)d_in[3];
    float* out = (float*)d_out;

    nw_regression_kernel<<<N_ROWS, BLOCK, 0, stream>>>(queries, keys, values, w, out);
}